// Round 10
// baseline (181.417 us; speedup 1.0000x reference)
//
#include <hip/hip_runtime.h>
#include <stdint.h>
#include <math.h>

constexpr int BROWS = 256;
constexpr int VCOLS = 128000;
constexpr int NQ    = 5;                 // fifth-rows: 25600 cols each
constexpr int QCOLS = VCOLS / NQ;        // 25600
constexpr int QV4   = QCOLS / 4;         // 6400 float4 per fifth
constexpr int NBLK  = BROWS * NQ;        // 1280 blocks = 5 per CU exactly
constexpr int NTHR  = 320;               // 5 waves
constexpr int NITER = QV4 / (NTHR * 4);  // 5 (4 float4s per thread per iter)

// ---------- sortable float -> uint mapping (order-isomorphic) ---------------
__device__ __forceinline__ uint32_t fmap(float v) {
  uint32_t b = __float_as_uint(v);
  return b ^ (uint32_t)(((int32_t)b >> 31) | 0x80000000);
}

// key = (sortable_value << 32) | ~idx  -> u64 max == (max value, then min idx)
__device__ __forceinline__ unsigned long long mkkey(uint32_t s, int idx) {
  return ((unsigned long long)s << 32) | (uint32_t)(~(uint32_t)idx);
}

__device__ __forceinline__ uint32_t rotl(uint32_t x, uint32_t r) {
  return __builtin_amdgcn_alignbit(x, x, 32u - r);
}

// ---------- 4-lockstep Threefry-2x32, key (0,1), partitionable --------------
// ks = [0, 1, 0x1BD11BDB]; counter (0, i); bits = out0 ^ out1.
// Inputs are x1-inits (= counter_lo + 1, first key-injection pre-applied).
__device__ __forceinline__ void tf4_bits(uint32_t i0, uint32_t i1, uint32_t i2,
                                         uint32_t i3, uint32_t o[4]) {
  uint32_t a0, a1, a2, a3;
  uint32_t b0 = i0, b1 = i1, b2 = i2, b3 = i3;
#define RND(r) \
  a0 += b0; b0 = rotl(b0, r) ^ a0; \
  a1 += b1; b1 = rotl(b1, r) ^ a1; \
  a2 += b2; b2 = rotl(b2, r) ^ a2; \
  a3 += b3; b3 = rotl(b3, r) ^ a3;
  // round 1 with a==0 folded: a = b; b = rotl(b,13) ^ a
  a0 = b0; b0 = rotl(b0, 13u) ^ a0;
  a1 = b1; b1 = rotl(b1, 13u) ^ a1;
  a2 = b2; b2 = rotl(b2, 13u) ^ a2;
  a3 = b3; b3 = rotl(b3, 13u) ^ a3;
  RND(15u) RND(26u) RND(6u)
  a0 += 1u; a1 += 1u; a2 += 1u; a3 += 1u;
  b0 += 0x1BD11BDCu; b1 += 0x1BD11BDCu; b2 += 0x1BD11BDCu; b3 += 0x1BD11BDCu;
  RND(17u) RND(29u) RND(16u) RND(24u)
  a0 += 0x1BD11BDBu; a1 += 0x1BD11BDBu; a2 += 0x1BD11BDBu; a3 += 0x1BD11BDBu;
  b0 += 2u; b1 += 2u; b2 += 2u; b3 += 2u;
  RND(13u) RND(15u) RND(26u) RND(6u)
  b0 += 4u; b1 += 4u; b2 += 4u; b3 += 4u;   // ks[1]+3 = 4; a += ks[0]==0
  RND(17u) RND(29u) RND(16u) RND(24u)
  a0 += 1u; a1 += 1u; a2 += 1u; a3 += 1u;
  b0 += 0x1BD11BDFu; b1 += 0x1BD11BDFu; b2 += 0x1BD11BDFu; b3 += 0x1BD11BDFu; // ks[2]+4
  RND(13u) RND(15u) RND(26u) RND(6u)
  a0 += 0x1BD11BDBu; a1 += 0x1BD11BDBu; a2 += 0x1BD11BDBu; a3 += 0x1BD11BDBu;
  b0 += 5u; b1 += 5u; b2 += 5u; b3 += 5u;
#undef RND
  o[0] = a0 ^ b0; o[1] = a1 ^ b1; o[2] = a2 ^ b2; o[3] = a3 ^ b3;
}

// ---------- block reduce of u64-max -----------------------------------------
template <int NT>
__device__ __forceinline__ unsigned long long blockMaxU64(unsigned long long v) {
  __shared__ unsigned long long s_w[NT / 64];
  const int wid = threadIdx.x >> 6, lane = threadIdx.x & 63;
  #pragma unroll
  for (int off = 32; off > 0; off >>= 1) {
    unsigned long long o = __shfl_xor(v, off, 64);
    if (o > v) v = o;
  }
  if (lane == 0) s_w[wid] = v;
  __syncthreads();
  if (threadIdx.x == 0) {
    #pragma unroll
    for (int w = 1; w < NT / 64; ++w) if (s_w[w] > v) v = s_w[w];
    s_w[0] = v;
  }
  __syncthreads();
  return s_w[0];
}

// ============ Fused kernel: race argmax (or greedy for t==0 rows) + ==========
// ============ last-block combine (replaces separate k1/k3 launches) ==========
// Sample value: val = l*c1 - log2|log2(2-f)|  (row-constant dropped — cannot
// change the row argmax). c1 = log2(e)/safe_t. noise==0 (f==1) -> val=+inf
// (matches reference ratio=+inf); no NaN possible (logits finite).
extern "C" __global__ void __launch_bounds__(NTHR)
k_fused(const float* __restrict__ logits,
        const float* __restrict__ temps,
        unsigned long long* __restrict__ gPart,
        unsigned long long* __restrict__ sPart,
        unsigned int* __restrict__ counter,
        int* __restrict__ out)
{
  const int blk = blockIdx.x;
  const int row = blk / NQ, q = blk % NQ;
  const float4* base =
      reinterpret_cast<const float4*>(logits + (size_t)row * VCOLS + q * QCOLS);

  const float t = temps[row];
  const uint32_t rowbase = (uint32_t)row * (uint32_t)VCOLS;

  if (t == 0.0f) {
    // -------- greedy raw-logit argmax over this chunk (rare path) ----------
    const int idx0 = q * QCOLS;
    unsigned long long best = 0ull;
    for (int vv = threadIdx.x; vv < QV4; vv += NTHR) {
      float4 l4 = base[vv];
      int v0 = idx0 + vv * 4;
      unsigned long long k0 = mkkey(fmap(l4.x), v0 + 0);
      unsigned long long k1 = mkkey(fmap(l4.y), v0 + 1);
      unsigned long long k2 = mkkey(fmap(l4.z), v0 + 2);
      unsigned long long k3 = mkkey(fmap(l4.w), v0 + 3);
      if (k1 > k0) k0 = k1;
      if (k3 > k2) k2 = k3;
      if (k2 > k0) k0 = k2;
      if (k0 > best) best = k0;
    }
    best = blockMaxU64<NTHR>(best);
    if (threadIdx.x == 0) gPart[blk] = best;
  } else {
    // -------- exponential-race argmax over this chunk ----------------------
    const float c1 = (1.0f / t) * 1.4426950408889634f;      // log2(e)/t
    const uint32_t Ce = rowbase + (uint32_t)(q * QCOLS) + 1u; // x1-init base

    float bv = -INFINITY; uint32_t bx = 0u;

    int vb = (int)threadIdx.x;
    float4 A0 = base[vb], A1 = base[vb + NTHR],
           A2 = base[vb + 2 * NTHR], A3 = base[vb + 3 * NTHR];

    #pragma unroll 1
    for (int it = 0; it < NITER; ++it) {
      const int nvb = vb + 4 * NTHR;
      float4 B0, B1, B2, B3;
      if (it + 1 < NITER) {                   // uniform branch; prefetch next
        B0 = base[nvb]; B1 = base[nvb + NTHR];
        B2 = base[nvb + 2 * NTHR]; B3 = base[nvb + 3 * NTHR];
      }

      const float4 As[4] = {A0, A1, A2, A3};
      #pragma unroll
      for (int u = 0; u < 4; ++u) {
        const uint32_t ce = Ce + (uint32_t)((vb + u * NTHR) * 4);
        const float lx[4] = {As[u].x, As[u].y, As[u].z, As[u].w};
        uint32_t bits[4];
        tf4_bits(ce, ce + 1u, ce + 2u, ce + 3u, bits);
        #pragma unroll
        for (uint32_t k = 0; k < 4; ++k) {
          // f in [1,2); 2-f exact (Sterbenz); g = log2(2-f) = log2(1-u).
          float f = __uint_as_float((bits[k] >> 9) | 0x3F800000u);
          float g = __builtin_amdgcn_logf(2.0f - f);          // v_log_f32
          float g2 = __builtin_amdgcn_logf(fabsf(g));         // log2|g|
          float val = fmaf(lx[k], c1, -g2);                   // +inf when g==0
          if (val > bv) { bv = val; bx = ce + k; }
        }
      }

      vb = nvb;
      A0 = B0; A1 = B1; A2 = B2; A3 = B3;
    }

    const int scol = (int)(bx - 1u - rowbase);
    unsigned long long sk = blockMaxU64<NTHR>(mkkey(fmap(bv), scol));
    if (threadIdx.x == 0) sPart[blk] = sk;
  }

  // -------- last-block combine (replaces k3) -------------------------------
  __shared__ bool amLast;
  __threadfence();                                   // publish partial
  if (threadIdx.x == 0) {
    unsigned int old = atomicAdd(counter, 1u);
    amLast = (old == (unsigned int)(NBLK - 1));
  }
  __syncthreads();
  if (amLast) {
    __threadfence();                                 // acquire all partials
    const int r = threadIdx.x;
    if (r < BROWS) {
      const bool greedy_row = (temps[r] == 0.0f);
      unsigned long long m = 0ull;
      const unsigned long long* part = greedy_row ? gPart : sPart;
      #pragma unroll
      for (int j = 0; j < NQ; ++j) {
        unsigned long long o = part[r * NQ + j];
        if (o > m) m = o;
      }
      out[r] = (int)(~(uint32_t)m);
    }
  }
}

extern "C" void kernel_launch(void* const* d_in, const int* in_sizes, int n_in,
                              void* d_out, int out_size, void* d_ws, size_t ws_size,
                              hipStream_t stream) {
  const float* logits = (const float*)d_in[0];
  const float* temps  = (const float*)d_in[1];
  int* out = (int*)d_out;

  unsigned long long* gPart = (unsigned long long*)d_ws;   // NBLK entries
  unsigned long long* sPart = gPart + NBLK;                // NBLK entries
  unsigned int* counter = (unsigned int*)(sPart + NBLK);   // 1 entry

  hipMemsetAsync(counter, 0, sizeof(unsigned int), stream);
  k_fused<<<NBLK, NTHR, 0, stream>>>(logits, temps, gPart, sPart, counter, out);
}

// Round 11
// 104.345 us; speedup vs baseline: 1.7386x; 1.7386x over previous
//
#include <hip/hip_runtime.h>
#include <stdint.h>
#include <math.h>

constexpr int BROWS = 256;
constexpr int VCOLS = 128000;
constexpr int NQ    = 5;                 // fifth-rows: 25600 cols each
constexpr int QCOLS = VCOLS / NQ;        // 25600
constexpr int QV4   = QCOLS / 4;         // 6400 float4 per fifth
constexpr int NBLK  = BROWS * NQ;        // 1280 blocks = 5 per CU exactly
constexpr int NTHR  = 320;               // 5 waves
constexpr int NITER = QV4 / (NTHR * 4);  // 5 (4 float4s per thread per iter)
constexpr int CNT_STRIDE = 32;           // u32s -> 128 B per row counter line

// ---------- sortable float -> uint mapping (order-isomorphic) ---------------
__device__ __forceinline__ uint32_t fmap(float v) {
  uint32_t b = __float_as_uint(v);
  return b ^ (uint32_t)(((int32_t)b >> 31) | 0x80000000);
}

// key = (sortable_value << 32) | ~idx  -> u64 max == (max value, then min idx)
__device__ __forceinline__ unsigned long long mkkey(uint32_t s, int idx) {
  return ((unsigned long long)s << 32) | (uint32_t)(~(uint32_t)idx);
}

__device__ __forceinline__ uint32_t rotl(uint32_t x, uint32_t r) {
  return __builtin_amdgcn_alignbit(x, x, 32u - r);
}

// ---------- 4-lockstep Threefry-2x32, key (0,1), partitionable --------------
// ks = [0, 1, 0x1BD11BDB]; counter (0, i); bits = out0 ^ out1.
// Inputs are x1-inits (= counter_lo + 1, first key-injection pre-applied).
__device__ __forceinline__ void tf4_bits(uint32_t i0, uint32_t i1, uint32_t i2,
                                         uint32_t i3, uint32_t o[4]) {
  uint32_t a0, a1, a2, a3;
  uint32_t b0 = i0, b1 = i1, b2 = i2, b3 = i3;
#define RND(r) \
  a0 += b0; b0 = rotl(b0, r) ^ a0; \
  a1 += b1; b1 = rotl(b1, r) ^ a1; \
  a2 += b2; b2 = rotl(b2, r) ^ a2; \
  a3 += b3; b3 = rotl(b3, r) ^ a3;
  // round 1 with a==0 folded: a = b; b = rotl(b,13) ^ a
  a0 = b0; b0 = rotl(b0, 13u) ^ a0;
  a1 = b1; b1 = rotl(b1, 13u) ^ a1;
  a2 = b2; b2 = rotl(b2, 13u) ^ a2;
  a3 = b3; b3 = rotl(b3, 13u) ^ a3;
  RND(15u) RND(26u) RND(6u)
  a0 += 1u; a1 += 1u; a2 += 1u; a3 += 1u;
  b0 += 0x1BD11BDCu; b1 += 0x1BD11BDCu; b2 += 0x1BD11BDCu; b3 += 0x1BD11BDCu;
  RND(17u) RND(29u) RND(16u) RND(24u)
  a0 += 0x1BD11BDBu; a1 += 0x1BD11BDBu; a2 += 0x1BD11BDBu; a3 += 0x1BD11BDBu;
  b0 += 2u; b1 += 2u; b2 += 2u; b3 += 2u;
  RND(13u) RND(15u) RND(26u) RND(6u)
  b0 += 4u; b1 += 4u; b2 += 4u; b3 += 4u;   // ks[1]+3 = 4; a += ks[0]==0
  RND(17u) RND(29u) RND(16u) RND(24u)
  a0 += 1u; a1 += 1u; a2 += 1u; a3 += 1u;
  b0 += 0x1BD11BDFu; b1 += 0x1BD11BDFu; b2 += 0x1BD11BDFu; b3 += 0x1BD11BDFu; // ks[2]+4
  RND(13u) RND(15u) RND(26u) RND(6u)
  a0 += 0x1BD11BDBu; a1 += 0x1BD11BDBu; a2 += 0x1BD11BDBu; a3 += 0x1BD11BDBu;
  b0 += 5u; b1 += 5u; b2 += 5u; b3 += 5u;
#undef RND
  o[0] = a0 ^ b0; o[1] = a1 ^ b1; o[2] = a2 ^ b2; o[3] = a3 ^ b3;
}

// ---------- block reduce of u64-max -----------------------------------------
template <int NT>
__device__ __forceinline__ unsigned long long blockMaxU64(unsigned long long v) {
  __shared__ unsigned long long s_w[NT / 64];
  const int wid = threadIdx.x >> 6, lane = threadIdx.x & 63;
  #pragma unroll
  for (int off = 32; off > 0; off >>= 1) {
    unsigned long long o = __shfl_xor(v, off, 64);
    if (o > v) v = o;
  }
  if (lane == 0) s_w[wid] = v;
  __syncthreads();
  if (threadIdx.x == 0) {
    #pragma unroll
    for (int w = 1; w < NT / 64; ++w) if (s_w[w] > v) v = s_w[w];
    s_w[0] = v;
  }
  __syncthreads();
  return s_w[0];
}

// ============ Fused: race argmax (+greedy for t==0 rows) + per-row combine ===
// Race value: val = l*c1 - log2|log2(2-f)|  (row-constant dropped — cannot
// change the row argmax). c1 = log2(e)/safe_t. noise==0 (f==1) -> val=+inf
// (matches reference ratio=+inf); no NaN possible (logits finite).
extern "C" __global__ void __launch_bounds__(NTHR)
k_fused(const float* __restrict__ logits,
        const float* __restrict__ temps,
        unsigned long long* __restrict__ gPart,
        unsigned long long* __restrict__ sPart,
        unsigned int* __restrict__ rowCnt,   // one line per row
        int* __restrict__ out)
{
  const int blk = blockIdx.x;
  const int row = blk / NQ, q = blk % NQ;
  const float4* base =
      reinterpret_cast<const float4*>(logits + (size_t)row * VCOLS + q * QCOLS);

  const float t = temps[row];
  const float safe_t = (t == 0.0f) ? 1.0f : t;
  const float c1 = (1.0f / safe_t) * 1.4426950408889634f;   // log2(e)/t
  const uint32_t rowbase = (uint32_t)row * (uint32_t)VCOLS;
  const uint32_t Ce = rowbase + (uint32_t)(q * QCOLS) + 1u; // x1-init base

  // -------- unconditional exponential-race argmax (R8-proven loop) ---------
  float bv = -INFINITY; uint32_t bx = 0u;

  int vb = (int)threadIdx.x;
  float4 A0 = base[vb], A1 = base[vb + NTHR],
         A2 = base[vb + 2 * NTHR], A3 = base[vb + 3 * NTHR];

  #pragma unroll 1
  for (int it = 0; it < NITER; ++it) {
    const int nvb = vb + 4 * NTHR;
    float4 B0, B1, B2, B3;
    if (it + 1 < NITER) {                     // uniform branch; prefetch next
      B0 = base[nvb]; B1 = base[nvb + NTHR];
      B2 = base[nvb + 2 * NTHR]; B3 = base[nvb + 3 * NTHR];
    }

    const float4 As[4] = {A0, A1, A2, A3};
    #pragma unroll
    for (int u = 0; u < 4; ++u) {
      const uint32_t ce = Ce + (uint32_t)((vb + u * NTHR) * 4);
      const float lx[4] = {As[u].x, As[u].y, As[u].z, As[u].w};
      uint32_t bits[4];
      tf4_bits(ce, ce + 1u, ce + 2u, ce + 3u, bits);
      #pragma unroll
      for (uint32_t k = 0; k < 4; ++k) {
        // f in [1,2); 2-f exact (Sterbenz); g = log2(2-f) = log2(1-u).
        float f = __uint_as_float((bits[k] >> 9) | 0x3F800000u);
        float g = __builtin_amdgcn_logf(2.0f - f);          // v_log_f32
        float g2 = __builtin_amdgcn_logf(fabsf(g));         // log2|g|
        float val = fmaf(lx[k], c1, -g2);                   // +inf when g==0
        if (val > bv) { bv = val; bx = ce + k; }
      }
    }

    vb = nvb;
    A0 = B0; A1 = B1; A2 = B2; A3 = B3;
  }

  const int scol = (int)(bx - 1u - rowbase);
  unsigned long long sk = blockMaxU64<NTHR>(mkkey(fmap(bv), scol));
  if (threadIdx.x == 0) sPart[blk] = sk;

  // -------- greedy raw-logit argmax, only when t==0 (block-uniform, rare) --
  if (t == 0.0f) {
    const int idx0 = q * QCOLS;
    unsigned long long gbest = 0ull;
    for (int vv = threadIdx.x; vv < QV4; vv += NTHR) {
      float4 l4 = base[vv];
      int v0 = idx0 + vv * 4;
      unsigned long long k0 = mkkey(fmap(l4.x), v0 + 0);
      unsigned long long k1 = mkkey(fmap(l4.y), v0 + 1);
      unsigned long long k2 = mkkey(fmap(l4.z), v0 + 2);
      unsigned long long k3 = mkkey(fmap(l4.w), v0 + 3);
      if (k1 > k0) k0 = k1;
      if (k3 > k2) k2 = k3;
      if (k2 > k0) k0 = k2;
      if (k0 > gbest) gbest = k0;
    }
    gbest = blockMaxU64<NTHR>(gbest);
    if (threadIdx.x == 0) gPart[blk] = gbest;
  }

  // -------- per-row last-block combine (one 128B counter line per row) -----
  if (threadIdx.x == 0) {
    __threadfence();                               // publish this block's partial
    unsigned int old = atomicAdd(&rowCnt[row * CNT_STRIDE], 1u);
    if (old == (unsigned int)(NQ - 1)) {           // last block of this row
      __threadfence();                             // acquire other partials
      const unsigned long long* part = (t == 0.0f) ? gPart : sPart;
      unsigned long long m = 0ull;
      #pragma unroll
      for (int j = 0; j < NQ; ++j) {
        unsigned long long o = part[row * NQ + j];
        if (o > m) m = o;
      }
      out[row] = (int)(~(uint32_t)m);
    }
  }
}

extern "C" void kernel_launch(void* const* d_in, const int* in_sizes, int n_in,
                              void* d_out, int out_size, void* d_ws, size_t ws_size,
                              hipStream_t stream) {
  const float* logits = (const float*)d_in[0];
  const float* temps  = (const float*)d_in[1];
  int* out = (int*)d_out;

  unsigned long long* gPart = (unsigned long long*)d_ws;     // NBLK entries
  unsigned long long* sPart = gPart + NBLK;                  // NBLK entries
  unsigned int* rowCnt = (unsigned int*)(sPart + NBLK);      // BROWS*CNT_STRIDE u32

  hipMemsetAsync(rowCnt, 0, BROWS * CNT_STRIDE * sizeof(unsigned int), stream);
  k_fused<<<NBLK, NTHR, 0, stream>>>(logits, temps, gPart, sPart, rowCnt, out);
}

// Round 12
// 80.330 us; speedup vs baseline: 2.2584x; 1.2990x over previous
//
#include <hip/hip_runtime.h>
#include <stdint.h>
#include <math.h>

constexpr int BROWS = 256;
constexpr int VCOLS = 128000;
constexpr int NQ    = 5;                 // fifth-rows: 25600 cols each
constexpr int QCOLS = VCOLS / NQ;        // 25600
constexpr int QV4   = QCOLS / 4;         // 6400 float4 per fifth
constexpr int NBLK  = BROWS * NQ;        // 1280 blocks = 5 per CU exactly
constexpr int NTHR  = 320;               // 5 waves
constexpr int NITER = QV4 / (NTHR * 4);  // 5 (4 float4s per thread per iter)

// ---------- sortable float -> uint mapping (order-isomorphic) ---------------
__device__ __forceinline__ uint32_t fmap(float v) {
  uint32_t b = __float_as_uint(v);
  return b ^ (uint32_t)(((int32_t)b >> 31) | 0x80000000);
}

// key = (sortable_value << 32) | ~idx  -> u64 max == (max value, then min idx)
__device__ __forceinline__ unsigned long long mkkey(uint32_t s, int idx) {
  return ((unsigned long long)s << 32) | (uint32_t)(~(uint32_t)idx);
}

__device__ __forceinline__ uint32_t rotl(uint32_t x, uint32_t r) {
  return __builtin_amdgcn_alignbit(x, x, 32u - r);
}

// ---------- 4-lockstep Threefry-2x32, key (0,1), partitionable --------------
// ks = [0, 1, 0x1BD11BDB]; counter (0, i); bits = out0 ^ out1.
// Inputs are x1-inits (= counter_lo + 1, first key-injection pre-applied).
__device__ __forceinline__ void tf4_bits(uint32_t i0, uint32_t i1, uint32_t i2,
                                         uint32_t i3, uint32_t o[4]) {
  uint32_t a0, a1, a2, a3;
  uint32_t b0 = i0, b1 = i1, b2 = i2, b3 = i3;
#define RND(r) \
  a0 += b0; b0 = rotl(b0, r) ^ a0; \
  a1 += b1; b1 = rotl(b1, r) ^ a1; \
  a2 += b2; b2 = rotl(b2, r) ^ a2; \
  a3 += b3; b3 = rotl(b3, r) ^ a3;
  // round 1 with a==0 folded: a = b; b = rotl(b,13) ^ a
  a0 = b0; b0 = rotl(b0, 13u) ^ a0;
  a1 = b1; b1 = rotl(b1, 13u) ^ a1;
  a2 = b2; b2 = rotl(b2, 13u) ^ a2;
  a3 = b3; b3 = rotl(b3, 13u) ^ a3;
  RND(15u) RND(26u) RND(6u)
  a0 += 1u; a1 += 1u; a2 += 1u; a3 += 1u;
  b0 += 0x1BD11BDCu; b1 += 0x1BD11BDCu; b2 += 0x1BD11BDCu; b3 += 0x1BD11BDCu;
  RND(17u) RND(29u) RND(16u) RND(24u)
  a0 += 0x1BD11BDBu; a1 += 0x1BD11BDBu; a2 += 0x1BD11BDBu; a3 += 0x1BD11BDBu;
  b0 += 2u; b1 += 2u; b2 += 2u; b3 += 2u;
  RND(13u) RND(15u) RND(26u) RND(6u)
  b0 += 4u; b1 += 4u; b2 += 4u; b3 += 4u;   // ks[1]+3 = 4; a += ks[0]==0
  RND(17u) RND(29u) RND(16u) RND(24u)
  a0 += 1u; a1 += 1u; a2 += 1u; a3 += 1u;
  b0 += 0x1BD11BDFu; b1 += 0x1BD11BDFu; b2 += 0x1BD11BDFu; b3 += 0x1BD11BDFu; // ks[2]+4
  RND(13u) RND(15u) RND(26u) RND(6u)
  a0 += 0x1BD11BDBu; a1 += 0x1BD11BDBu; a2 += 0x1BD11BDBu; a3 += 0x1BD11BDBu;
  b0 += 5u; b1 += 5u; b2 += 5u; b3 += 5u;
#undef RND
  o[0] = a0 ^ b0; o[1] = a1 ^ b1; o[2] = a2 ^ b2; o[3] = a3 ^ b3;
}

// ---------- block reduce of u64-max -----------------------------------------
template <int NT>
__device__ __forceinline__ unsigned long long blockMaxU64(unsigned long long v) {
  __shared__ unsigned long long s_w[NT / 64];
  const int wid = threadIdx.x >> 6, lane = threadIdx.x & 63;
  #pragma unroll
  for (int off = 32; off > 0; off >>= 1) {
    unsigned long long o = __shfl_xor(v, off, 64);
    if (o > v) v = o;
  }
  if (lane == 0) s_w[wid] = v;
  __syncthreads();
  if (threadIdx.x == 0) {
    #pragma unroll
    for (int w = 1; w < NT / 64; ++w) if (s_w[w] > v) v = s_w[w];
    s_w[0] = v;
  }
  __syncthreads();
  return s_w[0];
}

// ============ K-main: exponential-race argmax only (R8-proven loop) =========
// val = l*c1 - log2|log2(2-f)|  (row-constant dropped — cannot change the
// argmax). c1 = log2(e)/safe_t. noise==0 (f==1) -> val=+inf (matches ref);
// no NaN possible (logits finite).
extern "C" __global__ void __launch_bounds__(NTHR)
k_main(const float* __restrict__ logits,
       const float* __restrict__ temps,
       unsigned long long* __restrict__ sPart)
{
  const int blk = blockIdx.x;
  const int row = blk / NQ, q = blk % NQ;
  const float4* base =
      reinterpret_cast<const float4*>(logits + (size_t)row * VCOLS + q * QCOLS);

  const float t = temps[row];
  const float safe_t = (t == 0.0f) ? 1.0f : t;
  const float c1 = (1.0f / safe_t) * 1.4426950408889634f;   // log2(e)/t

  const uint32_t rowbase = (uint32_t)row * (uint32_t)VCOLS;
  const uint32_t Ce = rowbase + (uint32_t)(q * QCOLS) + 1u; // x1-init base

  float bv = -INFINITY; uint32_t bx = 0u;

  int vb = (int)threadIdx.x;
  float4 A0 = base[vb], A1 = base[vb + NTHR],
         A2 = base[vb + 2 * NTHR], A3 = base[vb + 3 * NTHR];

  #pragma unroll 1
  for (int it = 0; it < NITER; ++it) {
    const int nvb = vb + 4 * NTHR;
    float4 B0, B1, B2, B3;
    if (it + 1 < NITER) {                     // uniform branch; prefetch next
      B0 = base[nvb]; B1 = base[nvb + NTHR];
      B2 = base[nvb + 2 * NTHR]; B3 = base[nvb + 3 * NTHR];
    }

    const float4 As[4] = {A0, A1, A2, A3};
    #pragma unroll
    for (int u = 0; u < 4; ++u) {
      const uint32_t ce = Ce + (uint32_t)((vb + u * NTHR) * 4);
      const float lx[4] = {As[u].x, As[u].y, As[u].z, As[u].w};
      uint32_t bits[4];
      tf4_bits(ce, ce + 1u, ce + 2u, ce + 3u, bits);
      #pragma unroll
      for (uint32_t k = 0; k < 4; ++k) {
        // f in [1,2); 2-f exact (Sterbenz); g = log2(2-f) = log2(1-u).
        float f = __uint_as_float((bits[k] >> 9) | 0x3F800000u);
        float g = __builtin_amdgcn_logf(2.0f - f);          // v_log_f32
        float g2 = __builtin_amdgcn_logf(fabsf(g));         // log2|g|
        float val = fmaf(lx[k], c1, -g2);                   // +inf when g==0
        if (val > bv) { bv = val; bx = ce + k; }
      }
    }

    vb = nvb;
    A0 = B0; A1 = B1; A2 = B2; A3 = B3;
  }

  const int scol = (int)(bx - 1u - rowbase);
  unsigned long long sk = blockMaxU64<NTHR>(mkkey(fmap(bv), scol));
  if (threadIdx.x == 0) sPart[blk] = sk;
}

// ============ K1: greedy argmax, only for t==0 rows (usually none) ==========
extern "C" __global__ void __launch_bounds__(NTHR)
k1_greedy(const float* __restrict__ logits,
          const float* __restrict__ temps,
          unsigned long long* __restrict__ gPart)
{
  const int blk = blockIdx.x;
  const int row = blk / NQ, q = blk % NQ;
  if (temps[row] != 0.0f) return;           // uniform per-block early exit

  const float4* base =
      reinterpret_cast<const float4*>(logits + (size_t)row * VCOLS + q * QCOLS);
  const int idx0 = q * QCOLS;

  unsigned long long best = 0ull;
  for (int vv = threadIdx.x; vv < QV4; vv += NTHR) {
    float4 l4 = base[vv];
    int v0 = idx0 + vv * 4;
    unsigned long long k0 = mkkey(fmap(l4.x), v0 + 0);
    unsigned long long k1 = mkkey(fmap(l4.y), v0 + 1);
    unsigned long long k2 = mkkey(fmap(l4.z), v0 + 2);
    unsigned long long k3 = mkkey(fmap(l4.w), v0 + 3);
    if (k1 > k0) k0 = k1;
    if (k3 > k2) k2 = k3;
    if (k2 > k0) k0 = k2;
    if (k0 > best) best = k0;
  }
  best = blockMaxU64<NTHR>(best);
  if (threadIdx.x == 0) gPart[blk] = best;
}

// ================== K3: combine fifths, greedy/sample select ================
extern "C" __global__ void __launch_bounds__(BROWS)
k3_final(const float* __restrict__ temps,
         const unsigned long long* __restrict__ gPart,
         const unsigned long long* __restrict__ sPart,
         int* __restrict__ out)
{
  const int r = threadIdx.x;
  if (r >= BROWS) return;
  const bool greedy_row = (temps[r] == 0.0f);
  const unsigned long long* part = greedy_row ? gPart : sPart;
  unsigned long long m = 0ull;
  #pragma unroll
  for (int j = 0; j < NQ; ++j) {
    unsigned long long o = part[r * NQ + j];
    if (o > m) m = o;
  }
  out[r] = (int)(~(uint32_t)m);
}

extern "C" void kernel_launch(void* const* d_in, const int* in_sizes, int n_in,
                              void* d_out, int out_size, void* d_ws, size_t ws_size,
                              hipStream_t stream) {
  const float* logits = (const float*)d_in[0];
  const float* temps  = (const float*)d_in[1];
  int* out = (int*)d_out;

  unsigned long long* gPart = (unsigned long long*)d_ws;   // NBLK entries
  unsigned long long* sPart = gPart + NBLK;                // NBLK entries

  k_main<<<NBLK, NTHR, 0, stream>>>(logits, temps, sPart);
  k1_greedy<<<NBLK, NTHR, 0, stream>>>(logits, temps, gPart);
  k3_final<<<1, BROWS, 0, stream>>>(temps, gPart, sPart, out);
}

// Round 13
// 80.065 us; speedup vs baseline: 2.2659x; 1.0033x over previous
//
#include <hip/hip_runtime.h>
#include <stdint.h>
#include <math.h>

constexpr int BROWS = 256;
constexpr int VCOLS = 128000;
constexpr int NQ    = 5;                 // fifth-rows: 25600 cols each
constexpr int QCOLS = VCOLS / NQ;        // 25600
constexpr int QV4   = QCOLS / 4;         // 6400 float4 per fifth
constexpr int NBLK  = BROWS * NQ;        // 1280 blocks = 5 per CU exactly
constexpr int NTHR  = 320;               // 5 waves
constexpr int NITER = QV4 / (NTHR * 4);  // 5 (4 float4s per thread per iter)

// ---------- sortable float -> uint mapping (order-isomorphic) ---------------
__device__ __forceinline__ uint32_t fmap(float v) {
  uint32_t b = __float_as_uint(v);
  return b ^ (uint32_t)(((int32_t)b >> 31) | 0x80000000);
}

// key = (sortable_value << 32) | ~idx  -> u64 max == (max value, then min idx)
__device__ __forceinline__ unsigned long long mkkey(uint32_t s, int idx) {
  return ((unsigned long long)s << 32) | (uint32_t)(~(uint32_t)idx);
}

__device__ __forceinline__ uint32_t rotl(uint32_t x, uint32_t r) {
  return __builtin_amdgcn_alignbit(x, x, 32u - r);
}

// ---------- 4-lockstep Threefry-2x32, key (0,1), partitionable --------------
// ks = [0, 1, 0x1BD11BDB]; counter (0, i); bits = out0 ^ out1.
// Inputs are x1-inits (= counter_lo + 1, first key-injection pre-applied).
__device__ __forceinline__ void tf4_bits(uint32_t i0, uint32_t i1, uint32_t i2,
                                         uint32_t i3, uint32_t o[4]) {
  uint32_t a0, a1, a2, a3;
  uint32_t b0 = i0, b1 = i1, b2 = i2, b3 = i3;
#define RND(r) \
  a0 += b0; b0 = rotl(b0, r) ^ a0; \
  a1 += b1; b1 = rotl(b1, r) ^ a1; \
  a2 += b2; b2 = rotl(b2, r) ^ a2; \
  a3 += b3; b3 = rotl(b3, r) ^ a3;
  // round 1 with a==0 folded: a = b; b = rotl(b,13) ^ a
  a0 = b0; b0 = rotl(b0, 13u) ^ a0;
  a1 = b1; b1 = rotl(b1, 13u) ^ a1;
  a2 = b2; b2 = rotl(b2, 13u) ^ a2;
  a3 = b3; b3 = rotl(b3, 13u) ^ a3;
  RND(15u) RND(26u) RND(6u)
  a0 += 1u; a1 += 1u; a2 += 1u; a3 += 1u;
  b0 += 0x1BD11BDCu; b1 += 0x1BD11BDCu; b2 += 0x1BD11BDCu; b3 += 0x1BD11BDCu;
  RND(17u) RND(29u) RND(16u) RND(24u)
  a0 += 0x1BD11BDBu; a1 += 0x1BD11BDBu; a2 += 0x1BD11BDBu; a3 += 0x1BD11BDBu;
  b0 += 2u; b1 += 2u; b2 += 2u; b3 += 2u;
  RND(13u) RND(15u) RND(26u) RND(6u)
  b0 += 4u; b1 += 4u; b2 += 4u; b3 += 4u;   // ks[1]+3 = 4; a += ks[0]==0
  RND(17u) RND(29u) RND(16u) RND(24u)
  a0 += 1u; a1 += 1u; a2 += 1u; a3 += 1u;
  b0 += 0x1BD11BDFu; b1 += 0x1BD11BDFu; b2 += 0x1BD11BDFu; b3 += 0x1BD11BDFu; // ks[2]+4
  RND(13u) RND(15u) RND(26u) RND(6u)
  a0 += 0x1BD11BDBu; a1 += 0x1BD11BDBu; a2 += 0x1BD11BDBu; a3 += 0x1BD11BDBu;
  b0 += 5u; b1 += 5u; b2 += 5u; b3 += 5u;
#undef RND
  o[0] = a0 ^ b0; o[1] = a1 ^ b1; o[2] = a2 ^ b2; o[3] = a3 ^ b3;
}

// ---------- block reduce of u64-max -----------------------------------------
template <int NT>
__device__ __forceinline__ unsigned long long blockMaxU64(unsigned long long v) {
  __shared__ unsigned long long s_w[NT / 64];
  const int wid = threadIdx.x >> 6, lane = threadIdx.x & 63;
  #pragma unroll
  for (int off = 32; off > 0; off >>= 1) {
    unsigned long long o = __shfl_xor(v, off, 64);
    if (o > v) v = o;
  }
  if (lane == 0) s_w[wid] = v;
  __syncthreads();
  if (threadIdx.x == 0) {
    #pragma unroll
    for (int w = 1; w < NT / 64; ++w) if (s_w[w] > v) v = s_w[w];
    s_w[0] = v;
  }
  __syncthreads();
  return s_w[0];
}

// ============ K-main: exponential-race argmax (pinned prefetch) =============
// val = l*c1 - log2|log2(2-f)|  (row-constant dropped — cannot change the
// argmax). c1 = log2(e)/safe_t. noise==0 (f==1) -> val=+inf (matches ref);
// no NaN possible (logits finite).
extern "C" __global__ void __launch_bounds__(NTHR, 1)
k_main(const float* __restrict__ logits,
       const float* __restrict__ temps,
       unsigned long long* __restrict__ sPart)
{
  const int blk = blockIdx.x;
  const int row = blk / NQ, q = blk % NQ;
  const float4* base =
      reinterpret_cast<const float4*>(logits + (size_t)row * VCOLS + q * QCOLS);

  const float t = temps[row];
  const float safe_t = (t == 0.0f) ? 1.0f : t;
  const float c1 = (1.0f / safe_t) * 1.4426950408889634f;   // log2(e)/t

  const uint32_t rowbase = (uint32_t)row * (uint32_t)VCOLS;
  const uint32_t Ce = rowbase + (uint32_t)(q * QCOLS) + 1u; // x1-init base

  float bv = -INFINITY; uint32_t bx = 0u;

  int vb = (int)threadIdx.x;
  float4 A0 = base[vb], A1 = base[vb + NTHR],
         A2 = base[vb + 2 * NTHR], A3 = base[vb + 3 * NTHR];

  #pragma unroll 1
  for (int it = 0; it < NITER; ++it) {
    const int nvb = vb + 4 * NTHR;
    float4 B0, B1, B2, B3;
    if (it + 1 < NITER) {                     // uniform branch; prefetch next
      B0 = base[nvb]; B1 = base[nvb + NTHR];
      B2 = base[nvb + 2 * NTHR]; B3 = base[nvb + 3 * NTHR];
    }
    // Pin the prefetch: forbid the scheduler from sinking the B-loads into
    // the compute below. Their s_waitcnt lands at the end-of-iteration
    // copies, so issue is early and the wait is covered by ~1400 slots.
    __builtin_amdgcn_sched_barrier(0);

    const float4 As[4] = {A0, A1, A2, A3};
    #pragma unroll
    for (int u = 0; u < 4; ++u) {
      const uint32_t ce = Ce + (uint32_t)((vb + u * NTHR) * 4);
      const float lx[4] = {As[u].x, As[u].y, As[u].z, As[u].w};
      uint32_t bits[4];
      tf4_bits(ce, ce + 1u, ce + 2u, ce + 3u, bits);
      #pragma unroll
      for (uint32_t k = 0; k < 4; ++k) {
        // f in [1,2); 2-f exact (Sterbenz); g = log2(2-f) = log2(1-u).
        float f = __uint_as_float((bits[k] >> 9) | 0x3F800000u);
        float g = __builtin_amdgcn_logf(2.0f - f);          // v_log_f32
        float g2 = __builtin_amdgcn_logf(fabsf(g));         // log2|g|
        float val = fmaf(lx[k], c1, -g2);                   // +inf when g==0
        if (val > bv) { bv = val; bx = ce + k; }
      }
    }

    vb = nvb;
    A0 = B0; A1 = B1; A2 = B2; A3 = B3;
  }

  const int scol = (int)(bx - 1u - rowbase);
  unsigned long long sk = blockMaxU64<NTHR>(mkkey(fmap(bv), scol));
  if (threadIdx.x == 0) sPart[blk] = sk;
}

// ============ K1: greedy argmax, only for t==0 rows (usually none) ==========
extern "C" __global__ void __launch_bounds__(NTHR)
k1_greedy(const float* __restrict__ logits,
          const float* __restrict__ temps,
          unsigned long long* __restrict__ gPart)
{
  const int blk = blockIdx.x;
  const int row = blk / NQ, q = blk % NQ;
  if (temps[row] != 0.0f) return;           // uniform per-block early exit

  const float4* base =
      reinterpret_cast<const float4*>(logits + (size_t)row * VCOLS + q * QCOLS);
  const int idx0 = q * QCOLS;

  unsigned long long best = 0ull;
  for (int vv = threadIdx.x; vv < QV4; vv += NTHR) {
    float4 l4 = base[vv];
    int v0 = idx0 + vv * 4;
    unsigned long long k0 = mkkey(fmap(l4.x), v0 + 0);
    unsigned long long k1 = mkkey(fmap(l4.y), v0 + 1);
    unsigned long long k2 = mkkey(fmap(l4.z), v0 + 2);
    unsigned long long k3 = mkkey(fmap(l4.w), v0 + 3);
    if (k1 > k0) k0 = k1;
    if (k3 > k2) k2 = k3;
    if (k2 > k0) k0 = k2;
    if (k0 > best) best = k0;
  }
  best = blockMaxU64<NTHR>(best);
  if (threadIdx.x == 0) gPart[blk] = best;
}

// ================== K3: combine fifths, greedy/sample select ================
extern "C" __global__ void __launch_bounds__(BROWS)
k3_final(const float* __restrict__ temps,
         const unsigned long long* __restrict__ gPart,
         const unsigned long long* __restrict__ sPart,
         int* __restrict__ out)
{
  const int r = threadIdx.x;
  if (r >= BROWS) return;
  const bool greedy_row = (temps[r] == 0.0f);
  const unsigned long long* part = greedy_row ? gPart : sPart;
  unsigned long long m = 0ull;
  #pragma unroll
  for (int j = 0; j < NQ; ++j) {
    unsigned long long o = part[r * NQ + j];
    if (o > m) m = o;
  }
  out[r] = (int)(~(uint32_t)m);
}

extern "C" void kernel_launch(void* const* d_in, const int* in_sizes, int n_in,
                              void* d_out, int out_size, void* d_ws, size_t ws_size,
                              hipStream_t stream) {
  const float* logits = (const float*)d_in[0];
  const float* temps  = (const float*)d_in[1];
  int* out = (int*)d_out;

  unsigned long long* gPart = (unsigned long long*)d_ws;   // NBLK entries
  unsigned long long* sPart = gPart + NBLK;                // NBLK entries

  k_main<<<NBLK, NTHR, 0, stream>>>(logits, temps, sPart);
  k1_greedy<<<NBLK, NTHR, 0, stream>>>(logits, temps, gPart);
  k3_final<<<1, BROWS, 0, stream>>>(temps, gPart, sPart, out);
}

// Round 14
// 78.697 us; speedup vs baseline: 2.3053x; 1.0174x over previous
//
#include <hip/hip_runtime.h>
#include <stdint.h>
#include <math.h>

constexpr int BROWS = 256;
constexpr int VCOLS = 128000;
constexpr int NQ    = 5;                 // fifth-rows: 25600 cols each
constexpr int QCOLS = VCOLS / NQ;        // 25600
constexpr int QV4   = QCOLS / 4;         // 6400 float4 per fifth
constexpr int NBLK  = BROWS * NQ;        // 1280 blocks = 5 per CU exactly
constexpr int NTHR  = 320;               // 5 waves
constexpr int NITER = QV4 / (NTHR * 4);  // 5 (4 float4s per thread per iter)

// ---------- sortable float -> uint mapping (order-isomorphic) ---------------
__device__ __forceinline__ uint32_t fmap(float v) {
  uint32_t b = __float_as_uint(v);
  return b ^ (uint32_t)(((int32_t)b >> 31) | 0x80000000);
}

// key = (sortable_value << 32) | ~idx  -> u64 max == (max value, then min idx)
__device__ __forceinline__ unsigned long long mkkey(uint32_t s, int idx) {
  return ((unsigned long long)s << 32) | (uint32_t)(~(uint32_t)idx);
}

__device__ __forceinline__ uint32_t rotl(uint32_t x, uint32_t r) {
  return __builtin_amdgcn_alignbit(x, x, 32u - r);
}

// ---------- 4-lockstep Threefry-2x32, key (0,1), partitionable --------------
// ks = [0, 1, 0x1BD11BDB]; counter (0, i); bits = out0 ^ out1.
// Inputs are x1-inits (= counter_lo + 1, first key-injection pre-applied).
__device__ __forceinline__ void tf4_bits(uint32_t i0, uint32_t i1, uint32_t i2,
                                         uint32_t i3, uint32_t o[4]) {
  uint32_t a0, a1, a2, a3;
  uint32_t b0 = i0, b1 = i1, b2 = i2, b3 = i3;
#define RND(r) \
  a0 += b0; b0 = rotl(b0, r) ^ a0; \
  a1 += b1; b1 = rotl(b1, r) ^ a1; \
  a2 += b2; b2 = rotl(b2, r) ^ a2; \
  a3 += b3; b3 = rotl(b3, r) ^ a3;
  // round 1 with a==0 folded: a = b; b = rotl(b,13) ^ a
  a0 = b0; b0 = rotl(b0, 13u) ^ a0;
  a1 = b1; b1 = rotl(b1, 13u) ^ a1;
  a2 = b2; b2 = rotl(b2, 13u) ^ a2;
  a3 = b3; b3 = rotl(b3, 13u) ^ a3;
  RND(15u) RND(26u) RND(6u)
  a0 += 1u; a1 += 1u; a2 += 1u; a3 += 1u;
  b0 += 0x1BD11BDCu; b1 += 0x1BD11BDCu; b2 += 0x1BD11BDCu; b3 += 0x1BD11BDCu;
  RND(17u) RND(29u) RND(16u) RND(24u)
  a0 += 0x1BD11BDBu; a1 += 0x1BD11BDBu; a2 += 0x1BD11BDBu; a3 += 0x1BD11BDBu;
  b0 += 2u; b1 += 2u; b2 += 2u; b3 += 2u;
  RND(13u) RND(15u) RND(26u) RND(6u)
  b0 += 4u; b1 += 4u; b2 += 4u; b3 += 4u;   // ks[1]+3 = 4; a += ks[0]==0
  RND(17u) RND(29u) RND(16u) RND(24u)
  a0 += 1u; a1 += 1u; a2 += 1u; a3 += 1u;
  b0 += 0x1BD11BDFu; b1 += 0x1BD11BDFu; b2 += 0x1BD11BDFu; b3 += 0x1BD11BDFu; // ks[2]+4
  RND(13u) RND(15u) RND(26u) RND(6u)
  a0 += 0x1BD11BDBu; a1 += 0x1BD11BDBu; a2 += 0x1BD11BDBu; a3 += 0x1BD11BDBu;
  b0 += 5u; b1 += 5u; b2 += 5u; b3 += 5u;
#undef RND
  o[0] = a0 ^ b0; o[1] = a1 ^ b1; o[2] = a2 ^ b2; o[3] = a3 ^ b3;
}

// ---------- block reduce of u64-max -----------------------------------------
template <int NT>
__device__ __forceinline__ unsigned long long blockMaxU64(unsigned long long v) {
  __shared__ unsigned long long s_w[NT / 64];
  const int wid = threadIdx.x >> 6, lane = threadIdx.x & 63;
  #pragma unroll
  for (int off = 32; off > 0; off >>= 1) {
    unsigned long long o = __shfl_xor(v, off, 64);
    if (o > v) v = o;
  }
  if (lane == 0) s_w[wid] = v;
  __syncthreads();
  if (threadIdx.x == 0) {
    #pragma unroll
    for (int w = 1; w < NT / 64; ++w) if (s_w[w] > v) v = s_w[w];
    s_w[0] = v;
  }
  __syncthreads();
  return s_w[0];
}

// ============ K-main: exponential-race argmax (R12-proven, unchanged) =======
// val = l*c1 - log2|log2(2-f)|  (row-constant dropped — cannot change the
// argmax). c1 = log2(e)/safe_t. noise==0 (f==1) -> val=+inf (matches ref);
// no NaN possible (logits finite).
extern "C" __global__ void __launch_bounds__(NTHR, 1)
k_main(const float* __restrict__ logits,
       const float* __restrict__ temps,
       unsigned long long* __restrict__ sPart)
{
  const int blk = blockIdx.x;
  const int row = blk / NQ, q = blk % NQ;
  const float4* base =
      reinterpret_cast<const float4*>(logits + (size_t)row * VCOLS + q * QCOLS);

  const float t = temps[row];
  const float safe_t = (t == 0.0f) ? 1.0f : t;
  const float c1 = (1.0f / safe_t) * 1.4426950408889634f;   // log2(e)/t

  const uint32_t rowbase = (uint32_t)row * (uint32_t)VCOLS;
  const uint32_t Ce = rowbase + (uint32_t)(q * QCOLS) + 1u; // x1-init base

  float bv = -INFINITY; uint32_t bx = 0u;

  int vb = (int)threadIdx.x;
  float4 A0 = base[vb], A1 = base[vb + NTHR],
         A2 = base[vb + 2 * NTHR], A3 = base[vb + 3 * NTHR];

  #pragma unroll 1
  for (int it = 0; it < NITER; ++it) {
    const int nvb = vb + 4 * NTHR;
    float4 B0, B1, B2, B3;
    if (it + 1 < NITER) {                     // uniform branch; prefetch next
      B0 = base[nvb]; B1 = base[nvb + NTHR];
      B2 = base[nvb + 2 * NTHR]; B3 = base[nvb + 3 * NTHR];
    }
    __builtin_amdgcn_sched_barrier(0);

    const float4 As[4] = {A0, A1, A2, A3};
    #pragma unroll
    for (int u = 0; u < 4; ++u) {
      const uint32_t ce = Ce + (uint32_t)((vb + u * NTHR) * 4);
      const float lx[4] = {As[u].x, As[u].y, As[u].z, As[u].w};
      uint32_t bits[4];
      tf4_bits(ce, ce + 1u, ce + 2u, ce + 3u, bits);
      #pragma unroll
      for (uint32_t k = 0; k < 4; ++k) {
        // f in [1,2); 2-f exact (Sterbenz); g = log2(2-f) = log2(1-u).
        float f = __uint_as_float((bits[k] >> 9) | 0x3F800000u);
        float g = __builtin_amdgcn_logf(2.0f - f);          // v_log_f32
        float g2 = __builtin_amdgcn_logf(fabsf(g));         // log2|g|
        float val = fmaf(lx[k], c1, -g2);                   // +inf when g==0
        if (val > bv) { bv = val; bx = ce + k; }
      }
    }

    vb = nvb;
    A0 = B0; A1 = B1; A2 = B2; A3 = B3;
  }

  const int scol = (int)(bx - 1u - rowbase);
  unsigned long long sk = blockMaxU64<NTHR>(mkkey(fmap(bv), scol));
  if (threadIdx.x == 0) sPart[blk] = sk;
}

// ====== K3: per-row combine; greedy full-row scan folded in (t==0 only) =====
// One block per row, 64 threads. Fast path (t!=0): reduce the row's 5 race
// partials. Rare path (t==0): scan the raw logits for the row argmax here —
// slower if ever taken, but correct, and saves the 1280-block k1 launch.
extern "C" __global__ void __launch_bounds__(64)
k3_final(const float* __restrict__ logits,
         const float* __restrict__ temps,
         const unsigned long long* __restrict__ sPart,
         int* __restrict__ out)
{
  const int r = blockIdx.x;
  const int lane = threadIdx.x;
  const float t = temps[r];

  if (t != 0.0f) {
    if (lane == 0) {
      unsigned long long m = 0ull;
      #pragma unroll
      for (int j = 0; j < NQ; ++j) {
        unsigned long long o = sPart[r * NQ + j];
        if (o > m) m = o;
      }
      out[r] = (int)(~(uint32_t)m);
    }
    return;
  }

  // ---- greedy raw-logit argmax over the whole row (rare path) -------------
  const float4* base = reinterpret_cast<const float4*>(logits + (size_t)r * VCOLS);
  unsigned long long best = 0ull;
  for (int vv = lane; vv < VCOLS / 4; vv += 64) {
    float4 l4 = base[vv];
    int v0 = vv * 4;
    unsigned long long k0 = mkkey(fmap(l4.x), v0 + 0);
    unsigned long long k1 = mkkey(fmap(l4.y), v0 + 1);
    unsigned long long k2 = mkkey(fmap(l4.z), v0 + 2);
    unsigned long long k3 = mkkey(fmap(l4.w), v0 + 3);
    if (k1 > k0) k0 = k1;
    if (k3 > k2) k2 = k3;
    if (k2 > k0) k0 = k2;
    if (k0 > best) best = k0;
  }
  #pragma unroll
  for (int off = 32; off > 0; off >>= 1) {
    unsigned long long o = __shfl_xor(best, off, 64);
    if (o > best) best = o;
  }
  if (lane == 0) out[r] = (int)(~(uint32_t)best);
}

extern "C" void kernel_launch(void* const* d_in, const int* in_sizes, int n_in,
                              void* d_out, int out_size, void* d_ws, size_t ws_size,
                              hipStream_t stream) {
  const float* logits = (const float*)d_in[0];
  const float* temps  = (const float*)d_in[1];
  int* out = (int*)d_out;

  unsigned long long* sPart = (unsigned long long*)d_ws;   // NBLK entries

  k_main<<<NBLK, NTHR, 0, stream>>>(logits, temps, sPart);
  k3_final<<<BROWS, 64, 0, stream>>>(logits, temps, sPart, out);
}